// Round 7
// baseline (459.149 us; speedup 1.0000x reference)
//
#include <hip/hip_runtime.h>
#include <hip/hip_bf16.h>
#include <cfloat>
#include <math.h>

#define N_NODES 20000
#define M_PAD   20096            // 157 * 128
#define N_EDGES 320000
#define TOT_E   (N_EDGES + N_NODES)
#define EPAD    512              // csr/wn overshoot slack for lockstep loops
#define IN_F    512
#define HID     256
#define HEADS   4
#define OUT_F   256
#define H1DIM   (HEADS * HID)    // 1024
#define NEG_SLOPE 0.2f

typedef __attribute__((ext_vector_type(8))) __bf16 bf16x8;
typedef __attribute__((ext_vector_type(4))) __bf16 bf16x4;
typedef __attribute__((ext_vector_type(4))) float f32x4;

__device__ __forceinline__ float lrelu(float x) { return x >= 0.f ? x : NEG_SLOPE * x; }
__device__ __forceinline__ float elu_lite(float x) { return x > 0.f ? x : __expf(x) - 1.f; }

// ---------------- CSR-by-dst build ----------------
__global__ void k_count(const int* __restrict__ ei, int* __restrict__ deg) {
  int e = blockIdx.x * 256 + threadIdx.x;
  if (e >= TOT_E) return;
  int dst = (e < N_EDGES) ? ei[N_EDGES + e] : (e - N_EDGES);
  atomicAdd(&deg[dst], 1);
}

__global__ void k_scan(const int* __restrict__ deg, int* __restrict__ off) {
  __shared__ int part[256];
  int tid = threadIdx.x;
  const int chunk = (N_NODES + 255) / 256;
  int s0 = tid * chunk;
  int s1 = s0 + chunk; if (s1 > N_NODES) s1 = N_NODES; if (s0 > N_NODES) s0 = N_NODES;
  int s = 0;
  for (int i = s0; i < s1; ++i) s += deg[i];
  part[tid] = s;
  __syncthreads();
  for (int d = 1; d < 256; d <<= 1) {
    int v = (tid >= d) ? part[tid - d] : 0;
    __syncthreads();
    part[tid] += v;
    __syncthreads();
  }
  int run = (tid == 0) ? 0 : part[tid - 1];
  for (int i = s0; i < s1; ++i) { off[i] = run; run += deg[i]; }
  if (tid == 255) off[N_NODES] = run;
}

__global__ void k_fill(const int* __restrict__ ei, const int* __restrict__ off,
                       int* __restrict__ cur, int* __restrict__ csr_src) {
  int e = blockIdx.x * 256 + threadIdx.x;
  if (e >= TOT_E) return;
  int src, dst;
  if (e < N_EDGES) { src = ei[e]; dst = ei[N_EDGES + e]; }
  else             { src = dst = e - N_EDGES; }
  int pos = atomicAdd(&cur[dst], 1);
  csr_src[off[dst] + pos] = src;
}

// ---------------- degree-sorted node permutation (counting sort) ----------------
__global__ void k_hist(const int* __restrict__ off, int* __restrict__ hist) {
  int n = blockIdx.x * 256 + threadIdx.x;
  if (n >= N_NODES) return;
  int d = off[n + 1] - off[n];
  atomicAdd(&hist[min(d, 255)], 1);
}

__global__ void k_hscan(const int* __restrict__ hist, int* __restrict__ hoff) {
  __shared__ int sh[256];
  int t = threadIdx.x;
  int v = hist[t];
  sh[t] = v;
  __syncthreads();
  for (int d = 1; d < 256; d <<= 1) {
    int x = (t >= d) ? sh[t - d] : 0;
    __syncthreads();
    sh[t] += x;
    __syncthreads();
  }
  hoff[t] = sh[t] - v;   // exclusive
}

__global__ void k_perm(const int* __restrict__ off, const int* __restrict__ hoff,
                       int* __restrict__ cur2, int* __restrict__ perm) {
  int n = blockIdx.x * 256 + threadIdx.x;
  if (n >= N_NODES) return;
  int b = min(off[n + 1] - off[n], 255);
  int pos = atomicAdd(&cur2[b], 1);
  perm[hoff[b] + pos] = n;
}

// ---------------- fp32 -> bf16 conversion ----------------
__global__ void k_f2b(const float* __restrict__ in, __bf16* __restrict__ out, int n4) {
  int i = blockIdx.x * 256 + threadIdx.x;
  if (i >= n4) return;
  float4 v = ((const float4*)in)[i];
  bf16x4 o = { (__bf16)v.x, (__bf16)v.y, (__bf16)v.z, (__bf16)v.w };
  ((bf16x4*)out)[i] = o;
}

// ---------------- fp32 [R][C] -> bf16 [C][R] transpose ----------------
__global__ void k_tr_f2b(const float* __restrict__ in, __bf16* __restrict__ out,
                         int R, int Cc) {
  __shared__ float tile[32][33];
  int c0 = blockIdx.x * 32, r0 = blockIdx.y * 32;
  int tx = threadIdx.x & 31, ty = threadIdx.x >> 5;
  for (int rr = ty; rr < 32; rr += 8)
    tile[rr][tx] = in[(size_t)(r0 + rr) * Cc + c0 + tx];
  __syncthreads();
  for (int rr = ty; rr < 32; rr += 8)
    out[(size_t)(c0 + rr) * R + r0 + tx] = (__bf16)tile[tx][rr];
}

// ---------------- MFMA bf16 GEMM: Cb[M,N] = A[M,K] @ Bt[N,K]^T  (bf16 out) ----------------
__global__ __launch_bounds__(256) void k_gemm_bf16(
    const __bf16* __restrict__ A,
    const __bf16* __restrict__ Bt,
    __bf16* __restrict__ Cb,
    int M, int N, int K)
{
  __shared__ char lds[32768];
  char* As = lds;
  char* Bs = lds + 16384;

  const int t = threadIdx.x;
  const int lane = t & 63;
  const int wid = t >> 6;
  const int wm = wid >> 1, wn = wid & 1;
  const int row0 = blockIdx.y * 128;
  const int col0 = blockIdx.x * 128;

  f32x4 acc[4][4];
#pragma unroll
  for (int i = 0; i < 4; ++i)
#pragma unroll
    for (int j = 0; j < 4; ++j) acc[i][j] = (f32x4){0.f, 0.f, 0.f, 0.f};

  for (int k0 = 0; k0 < K; k0 += 64) {
#pragma unroll
    for (int i = 0; i < 4; ++i) {
      int j = i * 256 + t;
      int r = j >> 3;
      int cc = (j & 7) ^ (r & 7);
      const __bf16* gp = A + (size_t)(row0 + r) * K + k0 + cc * 8;
      __builtin_amdgcn_global_load_lds(
          (const __attribute__((address_space(1))) void*)gp,
          (__attribute__((address_space(3))) void*)(As + j * 16), 16, 0, 0);
    }
#pragma unroll
    for (int i = 0; i < 4; ++i) {
      int j = i * 256 + t;
      int r = j >> 3;
      int cc = (j & 7) ^ (r & 7);
      const __bf16* gp = Bt + (size_t)(col0 + r) * K + k0 + cc * 8;
      __builtin_amdgcn_global_load_lds(
          (const __attribute__((address_space(1))) void*)gp,
          (__attribute__((address_space(3))) void*)(Bs + j * 16), 16, 0, 0);
    }
    __syncthreads();

#pragma unroll
    for (int ks = 0; ks < 2; ++ks) {
      bf16x8 af[4], bfr[4];
#pragma unroll
      for (int i = 0; i < 4; ++i) {
        int rA = wm * 64 + i * 16 + (lane & 15);
        int chA = (ks * 4 + (lane >> 4)) ^ (rA & 7);
        af[i] = *(const bf16x8*)(As + rA * 128 + chA * 16);
        int rB = wn * 64 + i * 16 + (lane & 15);
        int chB = (ks * 4 + (lane >> 4)) ^ (rB & 7);
        bfr[i] = *(const bf16x8*)(Bs + rB * 128 + chB * 16);
      }
#pragma unroll
      for (int i = 0; i < 4; ++i)
#pragma unroll
        for (int jn = 0; jn < 4; ++jn)
          acc[i][jn] = __builtin_amdgcn_mfma_f32_16x16x32_bf16(
              af[i], bfr[jn], acc[i][jn], 0, 0, 0);
    }
    __syncthreads();
  }

#pragma unroll
  for (int i = 0; i < 4; ++i) {
    int growb = row0 + wm * 64 + i * 16 + (lane >> 4) * 4;
#pragma unroll
    for (int jn = 0; jn < 4; ++jn) {
      int gcol = col0 + wn * 64 + jn * 16 + (lane & 15);
#pragma unroll
      for (int r = 0; r < 4; ++r) {
        int grow = growb + r;
        if (grow < M) Cb[(size_t)grow * N + gcol] = (__bf16)acc[i][jn][r];
      }
    }
  }
}

// ---------------- attention dot products (bf16 h) ----------------
__global__ void k_attn1(const __bf16* __restrict__ h1b, const float* __restrict__ att_s,
                        const float* __restrict__ att_d, float* __restrict__ as,
                        float* __restrict__ ad) {
  int n = blockIdx.x;
  int t = threadIdx.x;
  int head = t >> 6, lane = t & 63;
  bf16x4 hv = *(const bf16x4*)(h1b + (size_t)n * H1DIM + t * 4);
  float4 sv = *(const float4*)(att_s + t * 4);
  float4 dv = *(const float4*)(att_d + t * 4);
  float h0 = (float)hv[0], h1 = (float)hv[1], h2 = (float)hv[2], h3 = (float)hv[3];
  float ss = h0 * sv.x + h1 * sv.y + h2 * sv.z + h3 * sv.w;
  float sd = h0 * dv.x + h1 * dv.y + h2 * dv.z + h3 * dv.w;
#pragma unroll
  for (int d = 32; d; d >>= 1) { ss += __shfl_xor(ss, d); sd += __shfl_xor(sd, d); }
  if (lane == 0) { as[n * HEADS + head] = ss; ad[n * HEADS + head] = sd; }
}

__global__ void k_attn2(const __bf16* __restrict__ h2b, const float* __restrict__ att_s,
                        const float* __restrict__ att_d, float* __restrict__ as,
                        float* __restrict__ ad) {
  int n = blockIdx.x;
  int lane = threadIdx.x;
  bf16x4 hv = *(const bf16x4*)(h2b + (size_t)n * OUT_F + lane * 4);
  float4 sv = *(const float4*)(att_s + lane * 4);
  float4 dv = *(const float4*)(att_d + lane * 4);
  float h0 = (float)hv[0], h1 = (float)hv[1], h2 = (float)hv[2], h3 = (float)hv[3];
  float ss = h0 * sv.x + h1 * sv.y + h2 * sv.z + h3 * sv.w;
  float sd = h0 * dv.x + h1 * dv.y + h2 * dv.z + h3 * dv.w;
#pragma unroll
  for (int d = 32; d; d >>= 1) { ss += __shfl_xor(ss, d); sd += __shfl_xor(sd, d); }
  if (lane == 0) { as[n] = ss; ad[n] = sd; }
}

// ---------------- per-edge softmax weights (no-max exp: logits bounded) ----------------
__global__ void k_w1(const int* __restrict__ off, const int* __restrict__ csr,
                     const float* __restrict__ as, const float* __restrict__ ad,
                     float* __restrict__ wn, float* __restrict__ inv) {
  int n = blockIdx.x;
  int lane = threadIdx.x;   // 64
  int beg = off[n], end = off[n + 1];
  float4 adv = *(const float4*)&ad[n * 4];
  float p0 = 0.f, p1 = 0.f, p2 = 0.f, p3 = 0.f;
  for (int p = beg + lane; p < end; p += 64) {
    int s = csr[p];
    float4 av = *(const float4*)&as[s * 4];
    float w0 = __expf(lrelu(av.x + adv.x));
    float w1 = __expf(lrelu(av.y + adv.y));
    float w2 = __expf(lrelu(av.z + adv.z));
    float w3 = __expf(lrelu(av.w + adv.w));
    p0 += w0; p1 += w1; p2 += w2; p3 += w3;
    float4 wv = {w0, w1, w2, w3};
    *(float4*)&wn[(size_t)p * 4] = wv;
  }
#pragma unroll
  for (int d = 32; d; d >>= 1) {
    p0 += __shfl_xor(p0, d); p1 += __shfl_xor(p1, d);
    p2 += __shfl_xor(p2, d); p3 += __shfl_xor(p3, d);
  }
  if (lane == 0) {
    float4 iv = {1.f / (p0 + 1e-16f), 1.f / (p1 + 1e-16f),
                 1.f / (p2 + 1e-16f), 1.f / (p3 + 1e-16f)};
    *(float4*)&inv[n * 4] = iv;
  }
}

__global__ void k_w2(const int* __restrict__ off, const int* __restrict__ csr,
                     const float* __restrict__ as, const float* __restrict__ ad,
                     float* __restrict__ wn, float* __restrict__ inv) {
  int n = blockIdx.x;
  int lane = threadIdx.x;
  int beg = off[n], end = off[n + 1];
  float adv = ad[n];
  float ps = 0.f;
  for (int p = beg + lane; p < end; p += 64) {
    int s = csr[p];
    float w = __expf(lrelu(as[s] + adv));
    wn[p] = w;
    ps += w;
  }
#pragma unroll
  for (int d = 32; d; d >>= 1) ps += __shfl_xor(ps, d);
  if (lane == 0) inv[n] = 1.f / (ps + 1e-16f);
}

// ---------------- XCD-sharded sliced gather, degree-sorted, pipelined ----------------
// layer 1: 16 slices of 64 ch, 2 phases. Phase 0 = slices 0-7 (bid<5000),
// phase 1 = slices 8-15. slice&7 -> XCD; per-XCD L2 working set = 2.56 MB.
// Wave = 8 nodes (degree-sorted via perm) x 8 lanes x 8 ch. Predicated loads:
// overshoot lanes re-read row 0 (cached) instead of random rows.
__global__ __launch_bounds__(256) void k_gather1(
    const int* __restrict__ off, const int* __restrict__ csr,
    const int* __restrict__ perm, const __bf16* __restrict__ h1b,
    const float* __restrict__ wn, const float* __restrict__ inv,
    const float* __restrict__ b1, __bf16* __restrict__ heluB) {
  int bid = blockIdx.x;
  int phase = (bid >= 5000) ? 1 : 0;
  int r = bid - phase * 5000;
  int slice = (r & 7) | (phase << 3);    // 0..15
  int grp = r >> 3;                      // 0..624
  int cb = slice * 64;
  int head = slice >> 2;
  int w = threadIdx.x >> 6, lane = threadIdx.x & 63;
  int g = lane >> 3;                     // node within wave (0..7)
  int cg = lane & 7;                     // channel octet
  int n = perm[grp * 32 + w * 8 + g];
  int beg = off[n], end = off[n + 1];
  int deg = end - beg;
  int itmax = deg;
  itmax = max(itmax, __shfl_xor(itmax, 8));
  itmax = max(itmax, __shfl_xor(itmax, 16));
  itmax = max(itmax, __shfl_xor(itmax, 32));

  float acc[8] = {0.f, 0.f, 0.f, 0.f, 0.f, 0.f, 0.f, 0.f};
  const __bf16* hb = h1b + cb + cg * 8;

  // 1-deep software pipeline
  int s0 = csr[beg];
  float w0 = wn[(size_t)beg * 4 + head];
  uint4 u0 = *(const uint4*)(hb + (size_t)s0 * H1DIM);
  for (int i = 0; i < itmax; ++i) {
    bool v = (i + 1 < deg);
    int e1 = beg + i + 1;
    int s1 = v ? csr[e1] : 0;
    float w1 = v ? wn[(size_t)e1 * 4 + head] : 0.f;
    uint4 u1 = *(const uint4*)(hb + (size_t)s1 * H1DIM);
    acc[0] = fmaf(w0, __uint_as_float(u0.x << 16), acc[0]);
    acc[1] = fmaf(w0, __uint_as_float(u0.x & 0xffff0000u), acc[1]);
    acc[2] = fmaf(w0, __uint_as_float(u0.y << 16), acc[2]);
    acc[3] = fmaf(w0, __uint_as_float(u0.y & 0xffff0000u), acc[3]);
    acc[4] = fmaf(w0, __uint_as_float(u0.z << 16), acc[4]);
    acc[5] = fmaf(w0, __uint_as_float(u0.z & 0xffff0000u), acc[5]);
    acc[6] = fmaf(w0, __uint_as_float(u0.w << 16), acc[6]);
    acc[7] = fmaf(w0, __uint_as_float(u0.w & 0xffff0000u), acc[7]);
    u0 = u1; w0 = w1;
  }

  float iv = inv[n * 4 + head];
  float4 bv0 = *(const float4*)(b1 + cb + cg * 8);
  float4 bv1 = *(const float4*)(b1 + cb + cg * 8 + 4);
  float bb[8] = {bv0.x, bv0.y, bv0.z, bv0.w, bv1.x, bv1.y, bv1.z, bv1.w};
  bf16x8 o;
#pragma unroll
  for (int k = 0; k < 8; ++k) {
    float v = acc[k] * iv + bb[k];
    o[k] = (__bf16)elu_lite(v);
  }
  *(bf16x8*)(heluB + (size_t)n * H1DIM + cb + cg * 8) = o;
}

// layer 2: 4 slices of 64 ch; slice = bid&3 (XCD x serves slice x&3; 2.56 MB).
__global__ __launch_bounds__(256) void k_gather2(
    const int* __restrict__ off, const int* __restrict__ csr,
    const int* __restrict__ perm, const __bf16* __restrict__ h2b,
    const float* __restrict__ wn, const float* __restrict__ inv,
    const float* __restrict__ b2, float* __restrict__ out) {
  int bid = blockIdx.x;
  int slice = bid & 3;
  int grp = bid >> 2;
  int cb = slice * 64;
  int w = threadIdx.x >> 6, lane = threadIdx.x & 63;
  int g = lane >> 3;
  int cg = lane & 7;
  int n = perm[grp * 32 + w * 8 + g];
  int beg = off[n], end = off[n + 1];
  int deg = end - beg;
  int itmax = deg;
  itmax = max(itmax, __shfl_xor(itmax, 8));
  itmax = max(itmax, __shfl_xor(itmax, 16));
  itmax = max(itmax, __shfl_xor(itmax, 32));

  float acc[8] = {0.f, 0.f, 0.f, 0.f, 0.f, 0.f, 0.f, 0.f};
  const __bf16* hb = h2b + cb + cg * 8;

  int s0 = csr[beg];
  float w0 = wn[beg];
  uint4 u0 = *(const uint4*)(hb + (size_t)s0 * OUT_F);
  for (int i = 0; i < itmax; ++i) {
    bool v = (i + 1 < deg);
    int e1 = beg + i + 1;
    int s1 = v ? csr[e1] : 0;
    float w1 = v ? wn[e1] : 0.f;
    uint4 u1 = *(const uint4*)(hb + (size_t)s1 * OUT_F);
    acc[0] = fmaf(w0, __uint_as_float(u0.x << 16), acc[0]);
    acc[1] = fmaf(w0, __uint_as_float(u0.x & 0xffff0000u), acc[1]);
    acc[2] = fmaf(w0, __uint_as_float(u0.y << 16), acc[2]);
    acc[3] = fmaf(w0, __uint_as_float(u0.y & 0xffff0000u), acc[3]);
    acc[4] = fmaf(w0, __uint_as_float(u0.z << 16), acc[4]);
    acc[5] = fmaf(w0, __uint_as_float(u0.z & 0xffff0000u), acc[5]);
    acc[6] = fmaf(w0, __uint_as_float(u0.w << 16), acc[6]);
    acc[7] = fmaf(w0, __uint_as_float(u0.w & 0xffff0000u), acc[7]);
    u0 = u1; w0 = w1;
  }

  float iv = inv[n];
  float4 bv0 = *(const float4*)(b2 + cb + cg * 8);
  float4 bv1 = *(const float4*)(b2 + cb + cg * 8 + 4);
  float* op = out + (size_t)n * OUT_F + cb + cg * 8;
  float4 o0 = {acc[0] * iv + bv0.x, acc[1] * iv + bv0.y,
               acc[2] * iv + bv0.z, acc[3] * iv + bv0.w};
  float4 o1 = {acc[4] * iv + bv1.x, acc[5] * iv + bv1.y,
               acc[6] * iv + bv1.z, acc[7] * iv + bv1.w};
  *(float4*)op = o0;
  *(float4*)(op + 4) = o1;
}

// ---------------- launch ----------------
extern "C" void kernel_launch(void* const* d_in, const int* in_sizes, int n_in,
                              void* d_out, int out_size, void* d_ws, size_t ws_size,
                              hipStream_t stream) {
  const float* x      = (const float*)d_in[0];
  const int*   ei     = (const int*)d_in[1];
  const float* W1     = (const float*)d_in[2];
  const float* att_s1 = (const float*)d_in[3];
  const float* att_d1 = (const float*)d_in[4];
  const float* b1     = (const float*)d_in[5];
  const float* W2     = (const float*)d_in[6];
  const float* att_s2 = (const float*)d_in[7];
  const float* att_d2 = (const float*)d_in[8];
  const float* b2     = (const float*)d_in[9];
  float* out = (float*)d_out;

  char* w = (char*)d_ws;
  auto alloc = [&](size_t bytes) {
    char* p = w;
    w += (bytes + 255) & ~(size_t)255;
    return p;
  };
  int*    deg   = (int*)alloc((size_t)N_NODES * 4);
  int*    off   = (int*)alloc((size_t)(N_NODES + 1) * 4);
  int*    cur   = (int*)alloc((size_t)N_NODES * 4);
  int*    csr   = (int*)alloc((size_t)(TOT_E + EPAD) * 4);
  int*    hist  = (int*)alloc(256 * 4);
  int*    hoff  = (int*)alloc(256 * 4);
  int*    cur2  = (int*)alloc(256 * 4);
  int*    perm  = (int*)alloc((size_t)N_NODES * 4);
  float*  as1   = (float*)alloc((size_t)N_NODES * HEADS * 4);
  float*  ad1   = (float*)alloc((size_t)N_NODES * HEADS * 4);
  float*  as2   = (float*)alloc((size_t)N_NODES * 4);
  float*  ad2   = (float*)alloc((size_t)N_NODES * 4);
  float*  wn1   = (float*)alloc((size_t)(TOT_E + EPAD) * HEADS * 4);
  float*  inv1  = (float*)alloc((size_t)N_NODES * HEADS * 4);
  float*  wn2   = (float*)alloc((size_t)(TOT_E + EPAD) * 4);
  float*  inv2  = (float*)alloc((size_t)N_NODES * 4);
  __bf16* xb    = (__bf16*)alloc((size_t)M_PAD * IN_F * 2);
  __bf16* w1t   = (__bf16*)alloc((size_t)H1DIM * IN_F * 2);
  __bf16* w2t   = (__bf16*)alloc((size_t)OUT_F * H1DIM * 2);
  __bf16* h1b   = (__bf16*)alloc((size_t)M_PAD * H1DIM * 2);
  __bf16* heluB = (__bf16*)alloc((size_t)M_PAD * H1DIM * 2);
  __bf16* h2b   = (__bf16*)alloc((size_t)M_PAD * OUT_F * 2);
  if ((size_t)(w - (char*)d_ws) > ws_size) return;

  hipMemsetAsync(deg, 0, (size_t)N_NODES * 4, stream);
  hipMemsetAsync(cur, 0, (size_t)N_NODES * 4, stream);
  hipMemsetAsync(csr + TOT_E, 0, (size_t)EPAD * 4, stream);  // overshoot-safe
  hipMemsetAsync(hist, 0, 256 * 4, stream);
  hipMemsetAsync(cur2, 0, 256 * 4, stream);

  k_count<<<(TOT_E + 255) / 256, 256, 0, stream>>>(ei, deg);
  k_scan<<<1, 256, 0, stream>>>(deg, off);
  k_fill<<<(TOT_E + 255) / 256, 256, 0, stream>>>(ei, off, cur, csr);
  k_hist<<<(N_NODES + 255) / 256, 256, 0, stream>>>(off, hist);
  k_hscan<<<1, 256, 0, stream>>>(hist, hoff);
  k_perm<<<(N_NODES + 255) / 256, 256, 0, stream>>>(off, hoff, cur2, perm);

  int n4 = N_NODES * IN_F / 4;
  k_f2b<<<(n4 + 255) / 256, 256, 0, stream>>>(x, xb, n4);
  k_tr_f2b<<<dim3(H1DIM / 32, IN_F / 32), 256, 0, stream>>>(W1, w1t, IN_F, H1DIM);
  k_tr_f2b<<<dim3(OUT_F / 32, H1DIM / 32), 256, 0, stream>>>(W2, w2t, H1DIM, OUT_F);

  // layer 1
  k_gemm_bf16<<<dim3(H1DIM / 128, M_PAD / 128), 256, 0, stream>>>(
      xb, w1t, h1b, N_NODES, H1DIM, IN_F);
  k_attn1<<<N_NODES, 256, 0, stream>>>(h1b, att_s1, att_d1, as1, ad1);
  k_w1<<<N_NODES, 64, 0, stream>>>(off, csr, as1, ad1, wn1, inv1);
  k_gather1<<<10000, 256, 0, stream>>>(off, csr, perm, h1b, wn1, inv1, b1, heluB);

  // layer 2
  k_gemm_bf16<<<dim3(OUT_F / 128, M_PAD / 128), 256, 0, stream>>>(
      heluB, w2t, h2b, N_NODES, OUT_F, H1DIM);
  k_attn2<<<N_NODES, 64, 0, stream>>>(h2b, att_s2, att_d2, as2, ad2);
  k_w2<<<N_NODES, 64, 0, stream>>>(off, csr, as2, ad2, wn2, inv2);
  k_gather2<<<2500, 256, 0, stream>>>(off, csr, perm, h2b, wn2, inv2, b2, out);
}

// Round 8
// 303.626 us; speedup vs baseline: 1.5122x; 1.5122x over previous
//
#include <hip/hip_runtime.h>
#include <hip/hip_bf16.h>
#include <cfloat>
#include <math.h>

#define N_NODES 20000
#define M_PAD   20096            // 157 * 128
#define N_EDGES 320000
#define TOT_E   (N_EDGES + N_NODES)
#define EPAD    512              // csr/wn overshoot slack for lockstep loops
#define PS      (TOT_E + EPAD)   // plane stride for planar weights
#define IN_F    512
#define HID     256
#define HEADS   4
#define OUT_F   256
#define H1DIM   (HEADS * HID)    // 1024
#define NEG_SLOPE 0.2f

typedef __attribute__((ext_vector_type(8))) __bf16 bf16x8;
typedef __attribute__((ext_vector_type(4))) __bf16 bf16x4;
typedef __attribute__((ext_vector_type(4))) float f32x4;

__device__ __forceinline__ float lrelu(float x) { return x >= 0.f ? x : NEG_SLOPE * x; }
__device__ __forceinline__ float elu_lite(float x) { return x > 0.f ? x : __expf(x) - 1.f; }

// ---------------- CSR-by-dst build ----------------
__global__ void k_count(const int* __restrict__ ei, int* __restrict__ deg) {
  int e = blockIdx.x * 256 + threadIdx.x;
  if (e >= TOT_E) return;
  int dst = (e < N_EDGES) ? ei[N_EDGES + e] : (e - N_EDGES);
  atomicAdd(&deg[dst], 1);
}

__global__ void k_scan(const int* __restrict__ deg, int* __restrict__ off) {
  __shared__ int part[256];
  int tid = threadIdx.x;
  const int chunk = (N_NODES + 255) / 256;
  int s0 = tid * chunk;
  int s1 = s0 + chunk; if (s1 > N_NODES) s1 = N_NODES; if (s0 > N_NODES) s0 = N_NODES;
  int s = 0;
  for (int i = s0; i < s1; ++i) s += deg[i];
  part[tid] = s;
  __syncthreads();
  for (int d = 1; d < 256; d <<= 1) {
    int v = (tid >= d) ? part[tid - d] : 0;
    __syncthreads();
    part[tid] += v;
    __syncthreads();
  }
  int run = (tid == 0) ? 0 : part[tid - 1];
  for (int i = s0; i < s1; ++i) { off[i] = run; run += deg[i]; }
  if (tid == 255) off[N_NODES] = run;
}

__global__ void k_fill(const int* __restrict__ ei, const int* __restrict__ off,
                       int* __restrict__ cur, int* __restrict__ csr_src) {
  int e = blockIdx.x * 256 + threadIdx.x;
  if (e >= TOT_E) return;
  int src, dst;
  if (e < N_EDGES) { src = ei[e]; dst = ei[N_EDGES + e]; }
  else             { src = dst = e - N_EDGES; }
  int pos = atomicAdd(&cur[dst], 1);
  csr_src[off[dst] + pos] = src;
}

// ---------------- fp32 -> bf16 conversion ----------------
__global__ void k_f2b(const float* __restrict__ in, __bf16* __restrict__ out, int n4) {
  int i = blockIdx.x * 256 + threadIdx.x;
  if (i >= n4) return;
  float4 v = ((const float4*)in)[i];
  bf16x4 o = { (__bf16)v.x, (__bf16)v.y, (__bf16)v.z, (__bf16)v.w };
  ((bf16x4*)out)[i] = o;
}

// ---------------- fp32 [R][C] -> bf16 [C][R] transpose ----------------
__global__ void k_tr_f2b(const float* __restrict__ in, __bf16* __restrict__ out,
                         int R, int Cc) {
  __shared__ float tile[32][33];
  int c0 = blockIdx.x * 32, r0 = blockIdx.y * 32;
  int tx = threadIdx.x & 31, ty = threadIdx.x >> 5;
  for (int rr = ty; rr < 32; rr += 8)
    tile[rr][tx] = in[(size_t)(r0 + rr) * Cc + c0 + tx];
  __syncthreads();
  for (int rr = ty; rr < 32; rr += 8)
    out[(size_t)(c0 + rr) * R + r0 + tx] = (__bf16)tile[tx][rr];
}

// ---------------- MFMA bf16 GEMM: Cb[M,N] = A[M,K] @ Bt[N,K]^T  (bf16 out) ----------------
__global__ __launch_bounds__(256) void k_gemm_bf16(
    const __bf16* __restrict__ A,
    const __bf16* __restrict__ Bt,
    __bf16* __restrict__ Cb,
    int M, int N, int K)
{
  __shared__ char lds[32768];
  char* As = lds;
  char* Bs = lds + 16384;

  const int t = threadIdx.x;
  const int lane = t & 63;
  const int wid = t >> 6;
  const int wm = wid >> 1, wn = wid & 1;
  const int row0 = blockIdx.y * 128;
  const int col0 = blockIdx.x * 128;

  f32x4 acc[4][4];
#pragma unroll
  for (int i = 0; i < 4; ++i)
#pragma unroll
    for (int j = 0; j < 4; ++j) acc[i][j] = (f32x4){0.f, 0.f, 0.f, 0.f};

  for (int k0 = 0; k0 < K; k0 += 64) {
#pragma unroll
    for (int i = 0; i < 4; ++i) {
      int j = i * 256 + t;
      int r = j >> 3;
      int cc = (j & 7) ^ (r & 7);
      const __bf16* gp = A + (size_t)(row0 + r) * K + k0 + cc * 8;
      __builtin_amdgcn_global_load_lds(
          (const __attribute__((address_space(1))) void*)gp,
          (__attribute__((address_space(3))) void*)(As + j * 16), 16, 0, 0);
    }
#pragma unroll
    for (int i = 0; i < 4; ++i) {
      int j = i * 256 + t;
      int r = j >> 3;
      int cc = (j & 7) ^ (r & 7);
      const __bf16* gp = Bt + (size_t)(col0 + r) * K + k0 + cc * 8;
      __builtin_amdgcn_global_load_lds(
          (const __attribute__((address_space(1))) void*)gp,
          (__attribute__((address_space(3))) void*)(Bs + j * 16), 16, 0, 0);
    }
    __syncthreads();

#pragma unroll
    for (int ks = 0; ks < 2; ++ks) {
      bf16x8 af[4], bfr[4];
#pragma unroll
      for (int i = 0; i < 4; ++i) {
        int rA = wm * 64 + i * 16 + (lane & 15);
        int chA = (ks * 4 + (lane >> 4)) ^ (rA & 7);
        af[i] = *(const bf16x8*)(As + rA * 128 + chA * 16);
        int rB = wn * 64 + i * 16 + (lane & 15);
        int chB = (ks * 4 + (lane >> 4)) ^ (rB & 7);
        bfr[i] = *(const bf16x8*)(Bs + rB * 128 + chB * 16);
      }
#pragma unroll
      for (int i = 0; i < 4; ++i)
#pragma unroll
        for (int jn = 0; jn < 4; ++jn)
          acc[i][jn] = __builtin_amdgcn_mfma_f32_16x16x32_bf16(
              af[i], bfr[jn], acc[i][jn], 0, 0, 0);
    }
    __syncthreads();
  }

#pragma unroll
  for (int i = 0; i < 4; ++i) {
    int growb = row0 + wm * 64 + i * 16 + (lane >> 4) * 4;
#pragma unroll
    for (int jn = 0; jn < 4; ++jn) {
      int gcol = col0 + wn * 64 + jn * 16 + (lane & 15);
#pragma unroll
      for (int r = 0; r < 4; ++r) {
        int grow = growb + r;
        if (grow < M) Cb[(size_t)grow * N + gcol] = (__bf16)acc[i][jn][r];
      }
    }
  }
}

// ---------------- attention dot products (bf16 h) ----------------
__global__ void k_attn1(const __bf16* __restrict__ h1b, const float* __restrict__ att_s,
                        const float* __restrict__ att_d, float* __restrict__ as,
                        float* __restrict__ ad) {
  int n = blockIdx.x;
  int t = threadIdx.x;
  int head = t >> 6, lane = t & 63;
  bf16x4 hv = *(const bf16x4*)(h1b + (size_t)n * H1DIM + t * 4);
  float4 sv = *(const float4*)(att_s + t * 4);
  float4 dv = *(const float4*)(att_d + t * 4);
  float h0 = (float)hv[0], h1 = (float)hv[1], h2 = (float)hv[2], h3 = (float)hv[3];
  float ss = h0 * sv.x + h1 * sv.y + h2 * sv.z + h3 * sv.w;
  float sd = h0 * dv.x + h1 * dv.y + h2 * dv.z + h3 * dv.w;
#pragma unroll
  for (int d = 32; d; d >>= 1) { ss += __shfl_xor(ss, d); sd += __shfl_xor(sd, d); }
  if (lane == 0) { as[n * HEADS + head] = ss; ad[n * HEADS + head] = sd; }
}

__global__ void k_attn2(const __bf16* __restrict__ h2b, const float* __restrict__ att_s,
                        const float* __restrict__ att_d, float* __restrict__ as,
                        float* __restrict__ ad) {
  int n = blockIdx.x;
  int lane = threadIdx.x;
  bf16x4 hv = *(const bf16x4*)(h2b + (size_t)n * OUT_F + lane * 4);
  float4 sv = *(const float4*)(att_s + lane * 4);
  float4 dv = *(const float4*)(att_d + lane * 4);
  float h0 = (float)hv[0], h1 = (float)hv[1], h2 = (float)hv[2], h3 = (float)hv[3];
  float ss = h0 * sv.x + h1 * sv.y + h2 * sv.z + h3 * sv.w;
  float sd = h0 * dv.x + h1 * dv.y + h2 * dv.z + h3 * dv.w;
#pragma unroll
  for (int d = 32; d; d >>= 1) { ss += __shfl_xor(ss, d); sd += __shfl_xor(sd, d); }
  if (lane == 0) { as[n] = ss; ad[n] = sd; }
}

// ---------------- per-edge softmax weights, PLANAR [head][edge] ----------------
__global__ void k_w1(const int* __restrict__ off, const int* __restrict__ csr,
                     const float* __restrict__ as, const float* __restrict__ ad,
                     float* __restrict__ wnP, float* __restrict__ inv) {
  int n = blockIdx.x;
  int lane = threadIdx.x;   // 64
  int beg = off[n], end = off[n + 1];
  float4 adv = *(const float4*)&ad[n * 4];
  float p0 = 0.f, p1 = 0.f, p2 = 0.f, p3 = 0.f;
  for (int p = beg + lane; p < end; p += 64) {
    int s = csr[p];
    float4 av = *(const float4*)&as[s * 4];
    float w0 = __expf(lrelu(av.x + adv.x));
    float w1 = __expf(lrelu(av.y + adv.y));
    float w2 = __expf(lrelu(av.z + adv.z));
    float w3 = __expf(lrelu(av.w + adv.w));
    p0 += w0; p1 += w1; p2 += w2; p3 += w3;
    wnP[p] = w0;
    wnP[PS + p] = w1;
    wnP[2 * PS + p] = w2;
    wnP[3 * PS + p] = w3;
  }
#pragma unroll
  for (int d = 32; d; d >>= 1) {
    p0 += __shfl_xor(p0, d); p1 += __shfl_xor(p1, d);
    p2 += __shfl_xor(p2, d); p3 += __shfl_xor(p3, d);
  }
  if (lane == 0) {
    float4 iv = {1.f / (p0 + 1e-16f), 1.f / (p1 + 1e-16f),
                 1.f / (p2 + 1e-16f), 1.f / (p3 + 1e-16f)};
    *(float4*)&inv[n * 4] = iv;
  }
}

__global__ void k_w2(const int* __restrict__ off, const int* __restrict__ csr,
                     const float* __restrict__ as, const float* __restrict__ ad,
                     float* __restrict__ wn, float* __restrict__ inv) {
  int n = blockIdx.x;
  int lane = threadIdx.x;
  int beg = off[n], end = off[n + 1];
  float adv = ad[n];
  float ps = 0.f;
  for (int p = beg + lane; p < end; p += 64) {
    int s = csr[p];
    float w = __expf(lrelu(as[s] + adv));
    wn[p] = w;
    ps += w;
  }
#pragma unroll
  for (int d = 32; d; d >>= 1) ps += __shfl_xor(ps, d);
  if (lane == 0) inv[n] = 1.f / (ps + 1e-16f);
}

// ---------------- XCD-sharded sliced gather (R6 structure + predicated rows) ----------------
// layer 1: 8 slices of 128 ch; slice = bid&7 -> XCD. Wave = 4 sequential nodes
// x (16 lanes x 8 ch). Overshoot iterations read row 0 (L2-hot) and weight 0.
// Weight reads are planar per-head: contiguous 1.36 MB stream per slice pass.
__global__ __launch_bounds__(256) void k_gather1(
    const int* __restrict__ off, const int* __restrict__ csr,
    const __bf16* __restrict__ h1b, const float* __restrict__ wnP,
    const float* __restrict__ inv, const float* __restrict__ b1,
    __bf16* __restrict__ heluB) {
  int bid = blockIdx.x;
  int slice = bid & 7;
  int head = slice >> 1;
  int cb = slice * 128;
  int w = threadIdx.x >> 6, lane = threadIdx.x & 63;
  int g = lane >> 4;             // node within wave (0..3)
  int cg = lane & 15;            // 16B channel group
  int n = (bid >> 3) * 16 + w * 4 + g;
  int beg = off[n], end = off[n + 1];
  int deg = end - beg;
  int itmax = deg;
  itmax = max(itmax, __shfl_xor(itmax, 16));
  itmax = max(itmax, __shfl_xor(itmax, 32));

  float acc[8] = {0.f, 0.f, 0.f, 0.f, 0.f, 0.f, 0.f, 0.f};
  const __bf16* hb = h1b + cb + cg * 8;
  const float* wp = wnP + (size_t)head * PS;
#pragma unroll 2
  for (int i = 0; i < itmax; ++i) {
    int e = beg + i;                         // in-bounds: csr/wn padded
    bool v = (i < deg);
    int s = v ? csr[e] : 0;                  // overshoot -> row 0 (cached)
    float wv = v ? wp[e] : 0.f;
    uint4 u = *(const uint4*)(hb + (size_t)s * H1DIM);
    acc[0] = fmaf(wv, __uint_as_float(u.x << 16), acc[0]);
    acc[1] = fmaf(wv, __uint_as_float(u.x & 0xffff0000u), acc[1]);
    acc[2] = fmaf(wv, __uint_as_float(u.y << 16), acc[2]);
    acc[3] = fmaf(wv, __uint_as_float(u.y & 0xffff0000u), acc[3]);
    acc[4] = fmaf(wv, __uint_as_float(u.z << 16), acc[4]);
    acc[5] = fmaf(wv, __uint_as_float(u.z & 0xffff0000u), acc[5]);
    acc[6] = fmaf(wv, __uint_as_float(u.w << 16), acc[6]);
    acc[7] = fmaf(wv, __uint_as_float(u.w & 0xffff0000u), acc[7]);
  }

  float iv = inv[n * 4 + head];
  float4 bv0 = *(const float4*)(b1 + cb + cg * 8);
  float4 bv1 = *(const float4*)(b1 + cb + cg * 8 + 4);
  float bb[8] = {bv0.x, bv0.y, bv0.z, bv0.w, bv1.x, bv1.y, bv1.z, bv1.w};
  bf16x8 o;
#pragma unroll
  for (int k = 0; k < 8; ++k) {
    float v = acc[k] * iv + bb[k];
    o[k] = (__bf16)elu_lite(v);
  }
  *(bf16x8*)(heluB + (size_t)n * H1DIM + cb + cg * 8) = o;
}

// layer 2: 4 slices of 64 ch; slice = bid&3. Wave = 8 nodes x (8 lanes x 8 ch).
__global__ __launch_bounds__(256) void k_gather2(
    const int* __restrict__ off, const int* __restrict__ csr,
    const __bf16* __restrict__ h2b, const float* __restrict__ wn,
    const float* __restrict__ inv, const float* __restrict__ b2,
    float* __restrict__ out) {
  int bid = blockIdx.x;
  int slice = bid & 3;
  int cb = slice * 64;
  int w = threadIdx.x >> 6, lane = threadIdx.x & 63;
  int g = lane >> 3;             // node within wave (0..7)
  int cg = lane & 7;             // 16B channel group
  int n = (bid >> 2) * 32 + w * 8 + g;
  int beg = off[n], end = off[n + 1];
  int deg = end - beg;
  int itmax = deg;
  itmax = max(itmax, __shfl_xor(itmax, 8));
  itmax = max(itmax, __shfl_xor(itmax, 16));
  itmax = max(itmax, __shfl_xor(itmax, 32));

  float acc[8] = {0.f, 0.f, 0.f, 0.f, 0.f, 0.f, 0.f, 0.f};
  const __bf16* hb = h2b + cb + cg * 8;
#pragma unroll 2
  for (int i = 0; i < itmax; ++i) {
    int e = beg + i;
    bool v = (i < deg);
    int s = v ? csr[e] : 0;
    float wv = v ? wn[e] : 0.f;
    uint4 u = *(const uint4*)(hb + (size_t)s * OUT_F);
    acc[0] = fmaf(wv, __uint_as_float(u.x << 16), acc[0]);
    acc[1] = fmaf(wv, __uint_as_float(u.x & 0xffff0000u), acc[1]);
    acc[2] = fmaf(wv, __uint_as_float(u.y << 16), acc[2]);
    acc[3] = fmaf(wv, __uint_as_float(u.y & 0xffff0000u), acc[3]);
    acc[4] = fmaf(wv, __uint_as_float(u.z << 16), acc[4]);
    acc[5] = fmaf(wv, __uint_as_float(u.z & 0xffff0000u), acc[5]);
    acc[6] = fmaf(wv, __uint_as_float(u.w << 16), acc[6]);
    acc[7] = fmaf(wv, __uint_as_float(u.w & 0xffff0000u), acc[7]);
  }

  float iv = inv[n];
  float4 bv0 = *(const float4*)(b2 + cb + cg * 8);
  float4 bv1 = *(const float4*)(b2 + cb + cg * 8 + 4);
  float* op = out + (size_t)n * OUT_F + cb + cg * 8;
  float4 o0 = {acc[0] * iv + bv0.x, acc[1] * iv + bv0.y,
               acc[2] * iv + bv0.z, acc[3] * iv + bv0.w};
  float4 o1 = {acc[4] * iv + bv1.x, acc[5] * iv + bv1.y,
               acc[6] * iv + bv1.z, acc[7] * iv + bv1.w};
  *(float4*)op = o0;
  *(float4*)(op + 4) = o1;
}

// ---------------- launch ----------------
extern "C" void kernel_launch(void* const* d_in, const int* in_sizes, int n_in,
                              void* d_out, int out_size, void* d_ws, size_t ws_size,
                              hipStream_t stream) {
  const float* x      = (const float*)d_in[0];
  const int*   ei     = (const int*)d_in[1];
  const float* W1     = (const float*)d_in[2];
  const float* att_s1 = (const float*)d_in[3];
  const float* att_d1 = (const float*)d_in[4];
  const float* b1     = (const float*)d_in[5];
  const float* W2     = (const float*)d_in[6];
  const float* att_s2 = (const float*)d_in[7];
  const float* att_d2 = (const float*)d_in[8];
  const float* b2     = (const float*)d_in[9];
  float* out = (float*)d_out;

  char* w = (char*)d_ws;
  auto alloc = [&](size_t bytes) {
    char* p = w;
    w += (bytes + 255) & ~(size_t)255;
    return p;
  };
  int*    deg   = (int*)alloc((size_t)N_NODES * 4);
  int*    off   = (int*)alloc((size_t)(N_NODES + 1) * 4);
  int*    cur   = (int*)alloc((size_t)N_NODES * 4);
  int*    csr   = (int*)alloc((size_t)PS * 4);
  float*  as1   = (float*)alloc((size_t)N_NODES * HEADS * 4);
  float*  ad1   = (float*)alloc((size_t)N_NODES * HEADS * 4);
  float*  as2   = (float*)alloc((size_t)N_NODES * 4);
  float*  ad2   = (float*)alloc((size_t)N_NODES * 4);
  float*  wnP   = (float*)alloc((size_t)PS * HEADS * 4);   // planar [head][edge]
  float*  inv1  = (float*)alloc((size_t)N_NODES * HEADS * 4);
  float*  wn2   = (float*)alloc((size_t)PS * 4);
  float*  inv2  = (float*)alloc((size_t)N_NODES * 4);
  __bf16* xb    = (__bf16*)alloc((size_t)M_PAD * IN_F * 2);
  __bf16* w1t   = (__bf16*)alloc((size_t)H1DIM * IN_F * 2);
  __bf16* w2t   = (__bf16*)alloc((size_t)OUT_F * H1DIM * 2);
  __bf16* h1b   = (__bf16*)alloc((size_t)M_PAD * H1DIM * 2);
  __bf16* heluB = (__bf16*)alloc((size_t)M_PAD * H1DIM * 2);
  __bf16* h2b   = (__bf16*)alloc((size_t)M_PAD * OUT_F * 2);
  if ((size_t)(w - (char*)d_ws) > ws_size) return;

  hipMemsetAsync(deg, 0, (size_t)N_NODES * 4, stream);
  hipMemsetAsync(cur, 0, (size_t)N_NODES * 4, stream);
  hipMemsetAsync(csr + TOT_E, 0, (size_t)EPAD * 4, stream);  // overshoot-safe

  k_count<<<(TOT_E + 255) / 256, 256, 0, stream>>>(ei, deg);
  k_scan<<<1, 256, 0, stream>>>(deg, off);
  k_fill<<<(TOT_E + 255) / 256, 256, 0, stream>>>(ei, off, cur, csr);

  int n4 = N_NODES * IN_F / 4;
  k_f2b<<<(n4 + 255) / 256, 256, 0, stream>>>(x, xb, n4);
  k_tr_f2b<<<dim3(H1DIM / 32, IN_F / 32), 256, 0, stream>>>(W1, w1t, IN_F, H1DIM);
  k_tr_f2b<<<dim3(OUT_F / 32, H1DIM / 32), 256, 0, stream>>>(W2, w2t, H1DIM, OUT_F);

  // layer 1
  k_gemm_bf16<<<dim3(H1DIM / 128, M_PAD / 128), 256, 0, stream>>>(
      xb, w1t, h1b, N_NODES, H1DIM, IN_F);
  k_attn1<<<N_NODES, 256, 0, stream>>>(h1b, att_s1, att_d1, as1, ad1);
  k_w1<<<N_NODES, 64, 0, stream>>>(off, csr, as1, ad1, wnP, inv1);
  k_gather1<<<(N_NODES / 16) * 8, 256, 0, stream>>>(off, csr, h1b, wnP, inv1, b1, heluB);

  // layer 2
  k_gemm_bf16<<<dim3(OUT_F / 128, M_PAD / 128), 256, 0, stream>>>(
      heluB, w2t, h2b, N_NODES, OUT_F, H1DIM);
  k_attn2<<<N_NODES, 64, 0, stream>>>(h2b, att_s2, att_d2, as2, ad2);
  k_w2<<<N_NODES, 64, 0, stream>>>(off, csr, as2, ad2, wn2, inv2);
  k_gather2<<<(N_NODES / 32) * 4, 256, 0, stream>>>(off, csr, h2b, wn2, inv2, b2, out);
}